// Round 1
// baseline (899.836 us; speedup 1.0000x reference)
//
#include <hip/hip_runtime.h>
#include <math.h>

// Problem dims (fixed by reference)
#define B_   4
#define L_   1024
#define D_   512
#define CHI_ 32
#define S_   4
#define BT_  (B_ * L_)       // 4096 rows
#define CSC_ (CHI_ * S_ * CHI_) // 4096 site cols

// ---------------------------------------------------------------------------
// Generic fp32 GEMM with bias: C[M,N] = A[M,K] @ B[K,N] + bias[N]
// 64x64 tile, BK=32, 256 threads, 4x4 per thread. M,N,K multiples of 64/64/32.
// ---------------------------------------------------------------------------
__global__ __launch_bounds__(256) void gemm_bias_kernel(
    const float* __restrict__ A, const float* __restrict__ Bm,
    const float* __restrict__ bias, float* __restrict__ C,
    int M, int N, int K)
{
    __shared__ float As[32][68];  // [k][m], padded: row stride 68 floats (16B aligned)
    __shared__ float Bs[32][64];  // [k][n]

    const int tid = threadIdx.x;
    const int tx = tid & 15;      // n-group
    const int ty = tid >> 4;      // m-group
    const int m0 = blockIdx.y * 64;
    const int n0 = blockIdx.x * 64;

    float c[4][4] = {};

    for (int k0 = 0; k0 < K; k0 += 32) {
        // --- load A tile 64x32 (each thread: 2 x float4, transposed into LDS) ---
        {
            const int o = tid * 8;
            const int m = o >> 5;          // tid/4
            const int k = o & 31;          // (tid%4)*8
            const float* ap = A + (size_t)(m0 + m) * K + k0 + k;
            const float4 a0 = *(const float4*)ap;
            const float4 a1 = *(const float4*)(ap + 4);
            As[k + 0][m] = a0.x; As[k + 1][m] = a0.y;
            As[k + 2][m] = a0.z; As[k + 3][m] = a0.w;
            As[k + 4][m] = a1.x; As[k + 5][m] = a1.y;
            As[k + 6][m] = a1.z; As[k + 7][m] = a1.w;
        }
        // --- load B tile 32x64 (each thread: 2 x float4) ---
        {
            const int o = tid * 8;
            const int k = o >> 6;          // tid/8
            const int n = o & 63;          // (tid%8)*8
            const float* bp = Bm + (size_t)(k0 + k) * N + n0 + n;
            *(float4*)&Bs[k][n]     = *(const float4*)bp;
            *(float4*)&Bs[k][n + 4] = *(const float4*)(bp + 4);
        }
        __syncthreads();

        #pragma unroll
        for (int kk = 0; kk < 32; ++kk) {
            const float4 av = *(const float4*)&As[kk][ty * 4];
            const float4 bv = *(const float4*)&Bs[kk][tx * 4];
            const float a[4] = {av.x, av.y, av.z, av.w};
            const float b[4] = {bv.x, bv.y, bv.z, bv.w};
            #pragma unroll
            for (int i = 0; i < 4; ++i)
                #pragma unroll
                for (int j = 0; j < 4; ++j)
                    c[i][j] = fmaf(a[i], b[j], c[i][j]);
        }
        __syncthreads();
    }

    // --- epilogue: add bias, store float4 rows ---
    const float4 bv = *(const float4*)&bias[n0 + tx * 4];
    #pragma unroll
    for (int i = 0; i < 4; ++i) {
        float4 outv;
        outv.x = c[i][0] + bv.x;
        outv.y = c[i][1] + bv.y;
        outv.z = c[i][2] + bv.z;
        outv.w = c[i][3] + bv.w;
        *(float4*)&C[(size_t)(m0 + ty * 4 + i) * N + n0 + tx * 4] = outv;
    }
}

// ---------------------------------------------------------------------------
// Abar[bt, l, r] = sum_p site[bt, l*128 + p*32 + r]   (4096 x 1024 outputs)
// ---------------------------------------------------------------------------
__global__ __launch_bounds__(256) void abar_kernel(
    const float* __restrict__ site, float* __restrict__ Abar)
{
    const int idx = blockIdx.x * 256 + threadIdx.x;   // over 4096*1024
    const int r  = idx & 31;
    const int l  = (idx >> 5) & 31;
    const int bt = idx >> 10;
    const float* sp = site + (size_t)bt * CSC_ + l * 128 + r;
    Abar[idx] = sp[0] + sp[32] + sp[64] + sp[96];
}

// ---------------------------------------------------------------------------
// Serial scan. One block (1 wave) per batch. Lane r holds h[r].
// v[r] = sum_l left[l] * Abar[t,l,r]; left broadcast via v_readlane -> SGPRs.
// Stores left_t = h_t + u_t for the parallel phase B.
// ---------------------------------------------------------------------------
__device__ __forceinline__ float readlane_f(float v, int l) {
    return __int_as_float(__builtin_amdgcn_readlane(__float_as_int(v), l));
}

__device__ __forceinline__ void scan_step(
    float& h, const float* __restrict__ a, float u, int t, int r, int tid,
    float* __restrict__ leftOut)
{
    const float left = h + u;
    if (tid < 32) leftOut[t * 32 + r] = left;   // fire-and-forget
    float acc0 = 0.f, acc1 = 0.f, acc2 = 0.f, acc3 = 0.f;
    #pragma unroll
    for (int l = 0; l < 32; l += 4) {
        acc0 = fmaf(readlane_f(left, l + 0), a[l + 0], acc0);
        acc1 = fmaf(readlane_f(left, l + 1), a[l + 1], acc1);
        acc2 = fmaf(readlane_f(left, l + 2), a[l + 2], acc2);
        acc3 = fmaf(readlane_f(left, l + 3), a[l + 3], acc3);
    }
    const float v = (acc0 + acc1) + (acc2 + acc3);
    float v2 = v * v;
    v2 += __shfl_xor(v2, 1);
    v2 += __shfl_xor(v2, 2);
    v2 += __shfl_xor(v2, 4);
    v2 += __shfl_xor(v2, 8);
    v2 += __shfl_xor(v2, 16);   // masks<32: halves reduce independently (lanes 32-63 mirror)
    h = v / (sqrtf(v2) + 1e-12f);
}

__device__ __forceinline__ void load_abar_row(
    float* __restrict__ dst, const float* __restrict__ Ab, int t, int r)
{
    #pragma unroll
    for (int l = 0; l < 32; ++l)
        dst[l] = Ab[t * 1024 + l * 32 + r];   // coalesced across lanes for each l
}

__global__ __launch_bounds__(64) void scan_kernel(
    const float* __restrict__ x, const float* __restrict__ Abar,
    float* __restrict__ leftOut)
{
    const int b   = blockIdx.x;
    const int tid = threadIdx.x;
    const int r   = tid & 31;           // lanes 32-63 mirror lanes 0-31

    const float* Ab = Abar + (size_t)b * L_ * 1024;
    const float* xb = x + (size_t)b * L_ * D_;
    float* lo = leftOut + (size_t)b * L_ * 32;

    float a0[32], a1[32], a2[32], a3[32];
    load_abar_row(a0, Ab, 0, r);
    load_abar_row(a1, Ab, 1, r);
    load_abar_row(a2, Ab, 2, r);
    load_abar_row(a3, Ab, 3, r);
    float u0 = xb[0 * D_ + r];
    float u1 = xb[1 * D_ + r];
    float u2 = xb[2 * D_ + r];
    float u3 = xb[3 * D_ + r];

    float h = 0.f;
    for (int t = 0; t < L_; t += 4) {
        int tl;
        scan_step(h, a0, u0, t + 0, r, tid, lo);
        tl = t + 4; if (tl > L_ - 1) tl = L_ - 1;
        load_abar_row(a0, Ab, tl, r);  u0 = xb[tl * D_ + r];

        scan_step(h, a1, u1, t + 1, r, tid, lo);
        tl = t + 5; if (tl > L_ - 1) tl = L_ - 1;
        load_abar_row(a1, Ab, tl, r);  u1 = xb[tl * D_ + r];

        scan_step(h, a2, u2, t + 2, r, tid, lo);
        tl = t + 6; if (tl > L_ - 1) tl = L_ - 1;
        load_abar_row(a2, Ab, tl, r);  u2 = xb[tl * D_ + r];

        scan_step(h, a3, u3, t + 3, r, tid, lo);
        tl = t + 7; if (tl > L_ - 1) tl = L_ - 1;
        load_abar_row(a3, Ab, tl, r);  u3 = xb[tl * D_ + r];
    }
}

// ---------------------------------------------------------------------------
// Phase B: for each (b,t): M[p,r] = sum_l left[l]*site[l,p,r]; then fuse the
// bridge: y1[j] = sum_{pr} M[pr] * W_bridge[pr,j] + b_bridge[j].
// ---------------------------------------------------------------------------
__global__ __launch_bounds__(128) void phaseB_kernel(
    const float* __restrict__ site, const float* __restrict__ leftBuf,
    const float* __restrict__ Wb, const float* __restrict__ bb,
    float* __restrict__ y1)
{
    __shared__ float lf[32];
    __shared__ float Ml[128];
    __shared__ float part[4][32];

    const int bt = blockIdx.x;
    const int tid = threadIdx.x;

    if (tid < 32) lf[tid] = leftBuf[bt * 32 + tid];
    __syncthreads();

    // M (no truncation: sigma_min/sigma_max of 4x32 Gaussian-like M >> 1e-4)
    const float* sp = site + (size_t)bt * CSC_ + tid;  // tid = p*32+r
    float acc = 0.f;
    #pragma unroll
    for (int l = 0; l < 32; ++l) acc = fmaf(lf[l], sp[l * 128], acc);
    Ml[tid] = acc;
    __syncthreads();

    const int j = tid & 31, q = tid >> 5;
    float p = 0.f;
    #pragma unroll
    for (int k = 0; k < 32; ++k)
        p = fmaf(Ml[q * 32 + k], Wb[(q * 32 + k) * 32 + j], p);
    part[q][j] = p;
    __syncthreads();

    if (tid < 32)
        y1[bt * 32 + tid] = part[0][tid] + part[1][tid] + part[2][tid]
                          + part[3][tid] + bb[tid];
}

// ---------------------------------------------------------------------------
// Epilogue: y = y1 @ W_out + b_out; LayerNorm; gated residual with x.
// One block per (b,t) row, 256 threads x 2 cols.
// ---------------------------------------------------------------------------
__global__ __launch_bounds__(256) void epilogue_kernel(
    const float* __restrict__ x, const float* __restrict__ y1buf,
    const float* __restrict__ Wout, const float* __restrict__ bout,
    const float* __restrict__ gamma, const float* __restrict__ beta,
    const float* __restrict__ gateZ, float* __restrict__ out)
{
    __shared__ float ys[32];
    __shared__ float red1[4], red2[4];

    const int bt = blockIdx.x;
    const int tid = threadIdx.x;

    if (tid < 32) ys[tid] = y1buf[bt * 32 + tid];
    __syncthreads();

    float yv[2];
    #pragma unroll
    for (int q = 0; q < 2; ++q) {
        const int d = tid + q * 256;
        float acc = bout[d];
        #pragma unroll
        for (int j = 0; j < 32; ++j)
            acc = fmaf(ys[j], Wout[j * D_ + d], acc);
        yv[q] = acc;
    }

    float s1 = yv[0] + yv[1];
    float s2 = yv[0] * yv[0] + yv[1] * yv[1];
    #pragma unroll
    for (int m = 1; m <= 32; m <<= 1) {
        s1 += __shfl_xor(s1, m);
        s2 += __shfl_xor(s2, m);
    }
    const int wid = tid >> 6;
    if ((tid & 63) == 0) { red1[wid] = s1; red2[wid] = s2; }
    __syncthreads();
    const float S1 = red1[0] + red1[1] + red1[2] + red1[3];
    const float S2 = red2[0] + red2[1] + red2[2] + red2[3];
    const float mu  = S1 * (1.f / (float)D_);
    const float var = S2 * (1.f / (float)D_) - mu * mu;
    const float rstd = rsqrtf(var + 1e-6f);

    #pragma unroll
    for (int q = 0; q < 2; ++q) {
        const int d = tid + q * 256;
        const size_t gi = (size_t)bt * D_ + d;
        const float yn = (yv[q] - mu) * rstd * gamma[d] + beta[d];
        const float z = gateZ[gi];
        const float g = 1.f / (1.f + expf(-z));
        const float xv = x[gi];
        out[gi] = g * yn + (1.f - g) * xv;
    }
}

// ---------------------------------------------------------------------------
extern "C" void kernel_launch(void* const* d_in, const int* in_sizes, int n_in,
                              void* d_out, int out_size, void* d_ws, size_t ws_size,
                              hipStream_t stream)
{
    const float* x        = (const float*)d_in[0];
    const float* W_site   = (const float*)d_in[1];
    const float* b_site   = (const float*)d_in[2];
    const float* W_bridge = (const float*)d_in[3];
    const float* b_bridge = (const float*)d_in[4];
    const float* W_out    = (const float*)d_in[5];
    const float* b_out    = (const float*)d_in[6];
    const float* gamma    = (const float*)d_in[7];
    const float* beta     = (const float*)d_in[8];
    const float* W_gate   = (const float*)d_in[9];
    const float* b_gate   = (const float*)d_in[10];
    float* out = (float*)d_out;

    float* ws = (float*)d_ws;
    float* site  = ws;                      // 4096*4096      = 16,777,216 f (64 MB)
    float* Abar  = site + (size_t)BT_ * CSC_;  // 4096*1024   =  4,194,304 f (16 MB)
    float* leftB = Abar + (size_t)BT_ * 1024;  // 4096*32     =    131,072 f
    float* y1    = leftB + (size_t)BT_ * CHI_; // 4096*32     =    131,072 f
    float* gateZ = Abar;                    // alias: Abar dead after scan (8 MB need <= 16 MB)

    // 1. site projection GEMM: site = x @ W_site + b_site   [4096 x 4096]
    gemm_bias_kernel<<<dim3(CSC_ / 64, BT_ / 64), dim3(256), 0, stream>>>(
        x, W_site, b_site, site, BT_, CSC_, D_);

    // 2. Abar[bt,l,r] = sum_p site
    abar_kernel<<<dim3(BT_ * 1024 / 256), dim3(256), 0, stream>>>(site, Abar);

    // 3. serial scan (4 blocks, 1 wave each) -> leftB
    scan_kernel<<<dim3(B_), dim3(64), 0, stream>>>(x, Abar, leftB);

    // 4. phase B: M = left . A, fused bridge -> y1
    phaseB_kernel<<<dim3(BT_), dim3(128), 0, stream>>>(
        site, leftB, W_bridge, b_bridge, y1);

    // 5. gate GEMM: gateZ = x @ W_gate + b_gate  (overwrites Abar region)
    gemm_bias_kernel<<<dim3(D_ / 64, BT_ / 64), dim3(256), 0, stream>>>(
        x, W_gate, b_gate, gateZ, BT_, D_, D_);

    // 6. epilogue: out-proj + LN + gated residual
    epilogue_kernel<<<dim3(BT_), dim3(256), 0, stream>>>(
        x, y1, W_out, b_out, gamma, beta, gateZ, out);
}

// Round 2
// 795.931 us; speedup vs baseline: 1.1305x; 1.1305x over previous
//
#include <hip/hip_runtime.h>
#include <math.h>

// Problem dims (fixed by reference)
#define B_   4
#define L_   1024
#define D_   512
#define CHI_ 32
#define S_   4
#define BT_  (B_ * L_)          // 4096 rows
#define CSC_ (CHI_ * S_ * CHI_) // 4096 site cols
#define DPRE 8                  // scan prefetch distance (register ring)

// ---------------------------------------------------------------------------
// Cross-lane helpers
// ---------------------------------------------------------------------------
__device__ __forceinline__ float readlane_f(float v, int l) {
    return __int_as_float(__builtin_amdgcn_readlane(__float_as_int(v), l));
}

template <int CTRL>
__device__ __forceinline__ float dpp_add(float x) {
    int y = __builtin_amdgcn_update_dpp(0, __float_as_int(x), CTRL, 0xf, 0xf, true);
    return x + __int_as_float(y);
}

// Sum of lanes 0..31 of x, valid in lane 31 (lanes 32..63 ignored).
__device__ __forceinline__ float reduce32_to_lane31(float x) {
    x = dpp_add<0x111>(x);  // row_shr:1
    x = dpp_add<0x112>(x);  // row_shr:2
    x = dpp_add<0x114>(x);  // row_shr:4
    x = dpp_add<0x118>(x);  // row_shr:8   -> lane15/31 hold row sums
    x = dpp_add<0x142>(x);  // row_bcast15 -> lane31 = sum(lanes 0..31)
    return x;
}

// ---------------------------------------------------------------------------
// Generic fp32 GEMM with bias: C[M,N] = A[M,K] @ B[K,N] + bias[N]
// 64x64 tile, BK=32, 256 threads, 4x4 per thread.
// ---------------------------------------------------------------------------
__global__ __launch_bounds__(256) void gemm_bias_kernel(
    const float* __restrict__ A, const float* __restrict__ Bm,
    const float* __restrict__ bias, float* __restrict__ C,
    int M, int N, int K)
{
    __shared__ float As[32][68];
    __shared__ float Bs[32][64];

    const int tid = threadIdx.x;
    const int tx = tid & 15;
    const int ty = tid >> 4;
    const int m0 = blockIdx.y * 64;
    const int n0 = blockIdx.x * 64;

    float c[4][4] = {};

    for (int k0 = 0; k0 < K; k0 += 32) {
        {
            const int o = tid * 8;
            const int m = o >> 5;
            const int k = o & 31;
            const float* ap = A + (size_t)(m0 + m) * K + k0 + k;
            const float4 a0 = *(const float4*)ap;
            const float4 a1 = *(const float4*)(ap + 4);
            As[k + 0][m] = a0.x; As[k + 1][m] = a0.y;
            As[k + 2][m] = a0.z; As[k + 3][m] = a0.w;
            As[k + 4][m] = a1.x; As[k + 5][m] = a1.y;
            As[k + 6][m] = a1.z; As[k + 7][m] = a1.w;
        }
        {
            const int o = tid * 8;
            const int k = o >> 6;
            const int n = o & 63;
            const float* bp = Bm + (size_t)(k0 + k) * N + n0 + n;
            *(float4*)&Bs[k][n]     = *(const float4*)bp;
            *(float4*)&Bs[k][n + 4] = *(const float4*)(bp + 4);
        }
        __syncthreads();

        #pragma unroll
        for (int kk = 0; kk < 32; ++kk) {
            const float4 av = *(const float4*)&As[kk][ty * 4];
            const float4 bv = *(const float4*)&Bs[kk][tx * 4];
            const float a[4] = {av.x, av.y, av.z, av.w};
            const float b[4] = {bv.x, bv.y, bv.z, bv.w};
            #pragma unroll
            for (int i = 0; i < 4; ++i)
                #pragma unroll
                for (int j = 0; j < 4; ++j)
                    c[i][j] = fmaf(a[i], b[j], c[i][j]);
        }
        __syncthreads();
    }

    const float4 bv = *(const float4*)&bias[n0 + tx * 4];
    #pragma unroll
    for (int i = 0; i < 4; ++i) {
        float4 outv;
        outv.x = c[i][0] + bv.x;
        outv.y = c[i][1] + bv.y;
        outv.z = c[i][2] + bv.z;
        outv.w = c[i][3] + bv.w;
        *(float4*)&C[(size_t)(m0 + ty * 4 + i) * N + n0 + tx * 4] = outv;
    }
}

// ---------------------------------------------------------------------------
// Prep: per (b,t) compute A_T[r][l] = sum_p site[l,p,r] (transposed for the
// scan's float4 row loads) and c[r] = sum_l u[l]*A[l][r].
// ---------------------------------------------------------------------------
__global__ __launch_bounds__(256) void prep_kernel(
    const float* __restrict__ site, const float* __restrict__ x,
    float* __restrict__ AbarT, float* __restrict__ cBuf)
{
    __shared__ float Al[32][33];   // A[l][r], padded
    __shared__ float uf[32];

    const int bt = blockIdx.x;
    const int tid = threadIdx.x;
    const int r = tid & 31;
    const int g = tid >> 5;        // 0..7

    if (tid < 32) uf[tid] = x[(size_t)bt * D_ + tid];

    const float* sp = site + (size_t)bt * CSC_;
    #pragma unroll
    for (int i = 0; i < 4; ++i) {
        const int l = i * 8 + g;
        const float* p = sp + l * 128 + r;
        Al[l][r] = p[0] + p[32] + p[64] + p[96];
    }
    __syncthreads();

    // write AbarT[bt][rr][ll] coalesced (ll = tid&31 fastest)
    float* At = AbarT + (size_t)bt * 1024;
    #pragma unroll
    for (int i = 0; i < 4; ++i) {
        const int rr = i * 8 + g;
        At[rr * 32 + r] = Al[r][rr];   // note: here 'r' plays the l role
    }

    // c[j] = sum_l u[l]*A[l][j]
    if (tid < 32) {
        float acc = 0.f;
        #pragma unroll
        for (int l = 0; l < 32; ++l)
            acc = fmaf(uf[l], Al[l][tid], acc);
        cBuf[(size_t)bt * 32 + tid] = acc;
    }
}

// ---------------------------------------------------------------------------
// Serial scan, homogeneous form. One wave per batch. Lane r holds w[r].
//   w_{t+1} = (w_t . A_t) * rsqrt(sum w_t^2) + c_t,    h_t = w_t/||w_t||.
// Norm-reduce (DPP) runs concurrently with the matvec (readlane broadcasts).
// A_T rows register-prefetched at distance DPRE to hide HBM latency.
// ---------------------------------------------------------------------------
__global__ __launch_bounds__(64, 1) void scan_kernel(
    const float* __restrict__ AbarT, const float* __restrict__ cBuf,
    float* __restrict__ wOut)
{
    const int b   = blockIdx.x;
    const int tid = threadIdx.x;
    const int r   = tid & 31;      // lanes 32-63 mirror lanes 0-31

    const float* At = AbarT + (size_t)b * L_ * 1024 + r * 32;
    const float* cb = cBuf  + (size_t)b * L_ * 32 + r;
    float*       wo = wOut  + (size_t)b * L_ * 64 + tid;

    float4 areg[DPRE][8];
    float  creg[DPRE];

    #pragma unroll
    for (int j = 0; j < DPRE; ++j) {
        const float* ap = At + (size_t)j * 1024;
        #pragma unroll
        for (int q = 0; q < 8; ++q) areg[j][q] = *(const float4*)(ap + q * 4);
        creg[j] = cb[j * 32];
    }

    float w = 0.f;   // ŵ_0 = 0  (h_0 = 0)

    for (int t = 0; t < L_; t += DPRE) {
        #pragma unroll
        for (int j = 0; j < DPRE; ++j) {
            wo[(t + j) * 64] = w;                       // store ŵ_t (all 64 lanes; mirror dup)

            // ---- norm chain (independent of matvec) ----
            float red = reduce32_to_lane31(w * w);

            // ---- matvec m[r] = sum_l w[l]*A[l][r], 8 chains of 4 ----
            float macc[8];
            #pragma unroll
            for (int q = 0; q < 8; ++q) {
                const float4 a = areg[j][q];
                float mq;
                mq = readlane_f(w, 4 * q + 0) * a.x;
                mq = fmaf(readlane_f(w, 4 * q + 1), a.y, mq);
                mq = fmaf(readlane_f(w, 4 * q + 2), a.z, mq);
                mq = fmaf(readlane_f(w, 4 * q + 3), a.w, mq);
                macc[q] = mq;
            }
            const float m = ((macc[0] + macc[1]) + (macc[2] + macc[3]))
                          + ((macc[4] + macc[5]) + (macc[6] + macc[7]));

            const float n2 = readlane_f(red, 31);
            const float rn = rsqrtf(n2 + 1e-24f);       // 0 * huge = 0 handles t=0
            w = fmaf(m, rn, creg[j]);

            // ---- prefetch row t+j+DPRE into this slot ----
            int tn = t + j + DPRE;
            if (tn > L_ - 1) tn = L_ - 1;
            const float* ap = At + (size_t)tn * 1024;
            #pragma unroll
            for (int q = 0; q < 8; ++q) areg[j][q] = *(const float4*)(ap + q * 4);
            creg[j] = cb[tn * 32];
        }
    }
}

// ---------------------------------------------------------------------------
// Phase B: normalize stored ŵ -> left = h + u; M = left.site; fused bridge.
// ---------------------------------------------------------------------------
__global__ __launch_bounds__(128) void phaseB_kernel(
    const float* __restrict__ site, const float* __restrict__ x,
    const float* __restrict__ wBuf,
    const float* __restrict__ Wb, const float* __restrict__ bb,
    float* __restrict__ y1)
{
    __shared__ float lf[32];
    __shared__ float Ml[128];
    __shared__ float part[4][32];

    const int bt = blockIdx.x;
    const int tid = threadIdx.x;

    if (tid < 64) {
        const float wv = wBuf[(size_t)bt * 64 + tid];   // lanes 32-63 hold mirror dup
        float red = reduce32_to_lane31(wv * wv);
        const float n2 = readlane_f(red, 31);
        const float rn = rsqrtf(n2 + 1e-24f);
        if (tid < 32)
            lf[tid] = fmaf(wv, rn, x[(size_t)bt * D_ + tid]);  // left = h + u
    }
    __syncthreads();

    // M[p,r] (no truncation; validated R1)
    const float* sp = site + (size_t)bt * CSC_ + tid;   // tid = p*32+r over l-stride 128
    float acc = 0.f;
    #pragma unroll
    for (int l = 0; l < 32; ++l) acc = fmaf(lf[l], sp[l * 128], acc);
    Ml[tid] = acc;
    __syncthreads();

    const int j = tid & 31, q = tid >> 5;
    float p = 0.f;
    #pragma unroll
    for (int k = 0; k < 32; ++k)
        p = fmaf(Ml[q * 32 + k], Wb[(q * 32 + k) * 32 + j], p);
    part[q][j] = p;
    __syncthreads();

    if (tid < 32)
        y1[bt * 32 + tid] = part[0][tid] + part[1][tid] + part[2][tid]
                          + part[3][tid] + bb[tid];
}

// ---------------------------------------------------------------------------
// Epilogue: y = y1 @ W_out + b_out; LayerNorm; gated residual with x.
// ---------------------------------------------------------------------------
__global__ __launch_bounds__(256) void epilogue_kernel(
    const float* __restrict__ x, const float* __restrict__ y1buf,
    const float* __restrict__ Wout, const float* __restrict__ bout,
    const float* __restrict__ gamma, const float* __restrict__ beta,
    const float* __restrict__ gateZ, float* __restrict__ out)
{
    __shared__ float ys[32];
    __shared__ float red1[4], red2[4];

    const int bt = blockIdx.x;
    const int tid = threadIdx.x;

    if (tid < 32) ys[tid] = y1buf[bt * 32 + tid];
    __syncthreads();

    float yv[2];
    #pragma unroll
    for (int q = 0; q < 2; ++q) {
        const int d = tid + q * 256;
        float acc = bout[d];
        #pragma unroll
        for (int j = 0; j < 32; ++j)
            acc = fmaf(ys[j], Wout[j * D_ + d], acc);
        yv[q] = acc;
    }

    float s1 = yv[0] + yv[1];
    float s2 = yv[0] * yv[0] + yv[1] * yv[1];
    #pragma unroll
    for (int m = 1; m <= 32; m <<= 1) {
        s1 += __shfl_xor(s1, m);
        s2 += __shfl_xor(s2, m);
    }
    const int wid = tid >> 6;
    if ((tid & 63) == 0) { red1[wid] = s1; red2[wid] = s2; }
    __syncthreads();
    const float S1 = red1[0] + red1[1] + red1[2] + red1[3];
    const float S2 = red2[0] + red2[1] + red2[2] + red2[3];
    const float mu  = S1 * (1.f / (float)D_);
    const float var = S2 * (1.f / (float)D_) - mu * mu;
    const float rstd = rsqrtf(var + 1e-6f);

    #pragma unroll
    for (int q = 0; q < 2; ++q) {
        const int d = tid + q * 256;
        const size_t gi = (size_t)bt * D_ + d;
        const float yn = (yv[q] - mu) * rstd * gamma[d] + beta[d];
        const float z = gateZ[gi];
        const float g = 1.f / (1.f + expf(-z));
        const float xv = x[gi];
        out[gi] = g * yn + (1.f - g) * xv;
    }
}

// ---------------------------------------------------------------------------
extern "C" void kernel_launch(void* const* d_in, const int* in_sizes, int n_in,
                              void* d_out, int out_size, void* d_ws, size_t ws_size,
                              hipStream_t stream)
{
    const float* x        = (const float*)d_in[0];
    const float* W_site   = (const float*)d_in[1];
    const float* b_site   = (const float*)d_in[2];
    const float* W_bridge = (const float*)d_in[3];
    const float* b_bridge = (const float*)d_in[4];
    const float* W_out    = (const float*)d_in[5];
    const float* b_out    = (const float*)d_in[6];
    const float* gamma    = (const float*)d_in[7];
    const float* beta     = (const float*)d_in[8];
    const float* W_gate   = (const float*)d_in[9];
    const float* b_gate   = (const float*)d_in[10];
    float* out = (float*)d_out;

    float* ws = (float*)d_ws;
    float* site  = ws;                           // 16,777,216 f (64 MB)
    float* AbarT = site  + (size_t)BT_ * CSC_;   //  4,194,304 f (16 MB)
    float* cBuf  = AbarT + (size_t)BT_ * 1024;   //    131,072 f
    float* wBuf  = cBuf  + (size_t)BT_ * 32;     //    262,144 f
    float* y1    = wBuf  + (size_t)BT_ * 64;     //    131,072 f
    float* gateZ = AbarT;                        // alias: AbarT dead after scan (needs 8 MB <= 16 MB)

    // 1. site projection GEMM: site = x @ W_site + b_site   [4096 x 4096]
    gemm_bias_kernel<<<dim3(CSC_ / 64, BT_ / 64), dim3(256), 0, stream>>>(
        x, W_site, b_site, site, BT_, CSC_, D_);

    // 2. prep: AbarT (transposed) + c = u.A  (fully parallel)
    prep_kernel<<<dim3(BT_), dim3(256), 0, stream>>>(site, x, AbarT, cBuf);

    // 3. serial scan (4 waves total) -> ŵ_t
    scan_kernel<<<dim3(B_), dim3(64), 0, stream>>>(AbarT, cBuf, wBuf);

    // 4. phase B: left = ŵ/||ŵ|| + u; M = left.site; fused bridge -> y1
    phaseB_kernel<<<dim3(BT_), dim3(128), 0, stream>>>(
        site, x, wBuf, W_bridge, b_bridge, y1);

    // 5. gate GEMM: gateZ = x @ W_gate + b_gate  (overwrites AbarT region)
    gemm_bias_kernel<<<dim3(D_ / 64, BT_ / 64), dim3(256), 0, stream>>>(
        x, W_gate, b_gate, gateZ, BT_, D_, D_);

    // 6. epilogue: out-proj + LN + gated residual
    epilogue_kernel<<<dim3(BT_), dim3(256), 0, stream>>>(
        x, y1, W_out, b_out, gamma, beta, gateZ, out);
}

// Round 4
// 571.124 us; speedup vs baseline: 1.5756x; 1.3936x over previous
//
#include <hip/hip_runtime.h>
#include <math.h>

// Problem dims (fixed by reference)
#define B_   4
#define L_   1024
#define D_   512
#define CHI_ 32
#define S_   4
#define BT_  (B_ * L_)          // 4096 rows
#define CSC_ (CHI_ * S_ * CHI_) // 4096 site cols
#define DPRE 8                  // scan prefetch distance (register ring)

// ---------------------------------------------------------------------------
// Cross-lane helpers
// ---------------------------------------------------------------------------
__device__ __forceinline__ float readlane_f(float v, int l) {
    return __int_as_float(__builtin_amdgcn_readlane(__float_as_int(v), l));
}

__device__ __forceinline__ float bpermute_f(int byte_idx, float v) {
    return __int_as_float(__builtin_amdgcn_ds_bpermute(byte_idx, __float_as_int(v)));
}

template <int CTRL>
__device__ __forceinline__ float dpp_add(float x) {
    int y = __builtin_amdgcn_update_dpp(0, __float_as_int(x), CTRL, 0xf, 0xf, true);
    return x + __int_as_float(y);
}

// Sum of lanes 0..31 of x, valid in lane 31 (row_shr accumulates toward
// HIGHER lanes — verified by R2 passing with readlane(.,31)).
__device__ __forceinline__ float reduce32_to_lane31(float x) {
    x = dpp_add<0x111>(x);  // row_shr:1
    x = dpp_add<0x112>(x);  // row_shr:2
    x = dpp_add<0x114>(x);  // row_shr:4
    x = dpp_add<0x118>(x);  // row_shr:8
    x = dpp_add<0x142>(x);  // row_bcast15 -> lane31 = sum(lanes 0..31)
    return x;
}

// Sum of 8 consecutive lanes (octet); complete sum lands in the TOP lane of
// each octet, i.e. lanes with (lane&7)==7.
__device__ __forceinline__ float octet_sum(float x) {
    x = dpp_add<0x111>(x);  // row_shr:1
    x = dpp_add<0x112>(x);  // row_shr:2
    x = dpp_add<0x114>(x);  // row_shr:4
    return x;
}

// ---------------------------------------------------------------------------
// Generic fp32 GEMM with bias: C[M,N] = A[M,K] @ B[K,N] + bias[N]
// ---------------------------------------------------------------------------
__global__ __launch_bounds__(256) void gemm_bias_kernel(
    const float* __restrict__ A, const float* __restrict__ Bm,
    const float* __restrict__ bias, float* __restrict__ C,
    int M, int N, int K)
{
    __shared__ float As[32][68];
    __shared__ float Bs[32][64];

    const int tid = threadIdx.x;
    const int tx = tid & 15;
    const int ty = tid >> 4;
    const int m0 = blockIdx.y * 64;
    const int n0 = blockIdx.x * 64;

    float c[4][4] = {};

    for (int k0 = 0; k0 < K; k0 += 32) {
        {
            const int o = tid * 8;
            const int m = o >> 5;
            const int k = o & 31;
            const float* ap = A + (size_t)(m0 + m) * K + k0 + k;
            const float4 a0 = *(const float4*)ap;
            const float4 a1 = *(const float4*)(ap + 4);
            As[k + 0][m] = a0.x; As[k + 1][m] = a0.y;
            As[k + 2][m] = a0.z; As[k + 3][m] = a0.w;
            As[k + 4][m] = a1.x; As[k + 5][m] = a1.y;
            As[k + 6][m] = a1.z; As[k + 7][m] = a1.w;
        }
        {
            const int o = tid * 8;
            const int k = o >> 6;
            const int n = o & 63;
            const float* bp = Bm + (size_t)(k0 + k) * N + n0 + n;
            *(float4*)&Bs[k][n]     = *(const float4*)bp;
            *(float4*)&Bs[k][n + 4] = *(const float4*)(bp + 4);
        }
        __syncthreads();

        #pragma unroll
        for (int kk = 0; kk < 32; ++kk) {
            const float4 av = *(const float4*)&As[kk][ty * 4];
            const float4 bv = *(const float4*)&Bs[kk][tx * 4];
            const float a[4] = {av.x, av.y, av.z, av.w};
            const float b[4] = {bv.x, bv.y, bv.z, bv.w};
            #pragma unroll
            for (int i = 0; i < 4; ++i)
                #pragma unroll
                for (int j = 0; j < 4; ++j)
                    c[i][j] = fmaf(a[i], b[j], c[i][j]);
        }
        __syncthreads();
    }

    const float4 bv = *(const float4*)&bias[n0 + tx * 4];
    #pragma unroll
    for (int i = 0; i < 4; ++i) {
        float4 outv;
        outv.x = c[i][0] + bv.x;
        outv.y = c[i][1] + bv.y;
        outv.z = c[i][2] + bv.z;
        outv.w = c[i][3] + bv.w;
        *(float4*)&C[(size_t)(m0 + ty * 4 + i) * N + n0 + tx * 4] = outv;
    }
}

// ---------------------------------------------------------------------------
// Prep: per (b,t) compute Abar[l][r] = sum_p site[l,p,r], then write it in
// the scan's interleaved layout:
//   flat[256q + 4i + e] = Abar[ 4*(i&7)+e ][ (i>>3) + 8q ],  i=0..63, q,e=0..3
// so the scan's q-th dwordx4 load (lane i at flat + 256q + 4i) is a fully
// contiguous 1KB wave transaction. Also c[r] = sum_l u[l]*Abar[l][r].
// ---------------------------------------------------------------------------
__global__ __launch_bounds__(256) void prep_kernel(
    const float* __restrict__ site, const float* __restrict__ x,
    float* __restrict__ AbarI, float* __restrict__ cBuf)
{
    __shared__ float Al[32][33];   // Abar[l][r], padded
    __shared__ float uf[32];

    const int bt = blockIdx.x;
    const int tid = threadIdx.x;
    const int r = tid & 31;
    const int g = tid >> 5;        // 0..7

    if (tid < 32) uf[tid] = x[(size_t)bt * D_ + tid];

    const float* sp = site + (size_t)bt * CSC_;
    #pragma unroll
    for (int i = 0; i < 4; ++i) {
        const int l = i * 8 + g;
        const float* p = sp + l * 128 + r;
        Al[l][r] = p[0] + p[32] + p[64] + p[96];
    }
    __syncthreads();

    // interleaved write: thread tid -> float4 at flat[4*tid]
    {
        const int i = tid & 63;
        const int q = tid >> 6;
        const int rr = (i >> 3) + 8 * q;
        const int l0 = 4 * (i & 7);
        float4 v;
        v.x = Al[l0 + 0][rr];
        v.y = Al[l0 + 1][rr];
        v.z = Al[l0 + 2][rr];
        v.w = Al[l0 + 3][rr];
        *(float4*)(AbarI + (size_t)bt * 1024 + 4 * tid) = v;
    }

    // c[j] = sum_l u[l]*Abar[l][j]
    if (tid < 32) {
        float acc = 0.f;
        #pragma unroll
        for (int l = 0; l < 32; ++l)
            acc = fmaf(uf[l], Al[l][tid], acc);
        cBuf[(size_t)bt * 32 + tid] = acc;
    }
}

// ---------------------------------------------------------------------------
// Serial scan, homogeneous form. One wave per batch.
//   w_{t+1} = (w_t . Abar_t) * rsqrt(sum w_t^2) + c_t
// w lives in standard layout: lane j holds w[j&31] (upper half duplicates).
// Per step, lane i owns Abar[l=4(i&7)+e][r=(i>>3)+8q] (16 floats, 4 float4);
// the full 32x32 matrix is spread over all 64 lanes (octets 0..7).
// Matvec: 4 bpermute broadcasts of w -> 16 fma -> octet DPP reduce (sum in
// octet TOP lane 8k+7) -> 4 bpermute redistribute + cndmask select.
// Ring of DPRE steps (128 VGPR) hides HBM latency.
// ---------------------------------------------------------------------------
__global__ __launch_bounds__(64, 1) void scan_kernel(
    const float* __restrict__ AbarI, const float* __restrict__ cBuf,
    float* __restrict__ wOut)
{
    const int b   = blockIdx.x;
    const int tid = threadIdx.x;

    const float* At = AbarI + (size_t)b * L_ * 1024 + 4 * tid;   // lane base
    const float* cb = cBuf  + (size_t)b * L_ * 32 + (tid & 31);
    float*       wo = wOut  + (size_t)b * L_ * 64 + tid;

    // broadcast indices (bytes): wbc_e = w[4*(tid&7)+e]
    const int idx0 = 16 * (tid & 7);
    // redistribute: octet sum lives in the octet TOP lane 8*(tid&7)+7
    // (R3 bug: pulled from leader 8*(tid&7), which holds only a partial sum)
    const int idxR = 32 * (tid & 7) + 28;
    // selection bits for q = (tid>>3)&3
    const bool selA = (tid >> 3) & 1;
    const bool selB = (tid >> 4) & 1;

    float4 areg[DPRE][4];
    float  creg[DPRE];

    #pragma unroll
    for (int j = 0; j < DPRE; ++j) {
        const float* ap = At + (size_t)j * 1024;
        #pragma unroll
        for (int q = 0; q < 4; ++q) areg[j][q] = *(const float4*)(ap + 256 * q);
        creg[j] = cb[j * 32];
    }

    float w = 0.f;   // w_0 = 0  (h_0 = 0)

    for (int t = 0; t < L_; t += DPRE) {
        #pragma unroll
        for (int j = 0; j < DPRE; ++j) {
            wo[(t + j) * 64] = w;                       // store w_t

            // ---- norm chain (independent of matvec) ----
            float red = reduce32_to_lane31(w * w);

            // ---- broadcasts: wbc_e = w[4*(tid&7)+e] ----
            const float wb0 = bpermute_f(idx0 + 0,  w);
            const float wb1 = bpermute_f(idx0 + 4,  w);
            const float wb2 = bpermute_f(idx0 + 8,  w);
            const float wb3 = bpermute_f(idx0 + 12, w);

            // ---- partials: p_q = sum_e wbc_e * A[l_e][r_q] ----
            float p0, p1, p2, p3;
            {
                const float4 a0 = areg[j][0], a1 = areg[j][1];
                const float4 a2 = areg[j][2], a3 = areg[j][3];
                p0 = fmaf(wb3, a0.w, fmaf(wb2, a0.z, fmaf(wb1, a0.y, wb0 * a0.x)));
                p1 = fmaf(wb3, a1.w, fmaf(wb2, a1.z, fmaf(wb1, a1.y, wb0 * a1.x)));
                p2 = fmaf(wb3, a2.w, fmaf(wb2, a2.z, fmaf(wb1, a2.y, wb0 * a2.x)));
                p3 = fmaf(wb3, a3.w, fmaf(wb2, a3.z, fmaf(wb1, a3.y, wb0 * a3.x)));
            }

            // ---- octet reduce: lane 8k+7 holds m[k+8q] in p_q ----
            p0 = octet_sum(p0);
            p1 = octet_sum(p1);
            p2 = octet_sum(p2);
            p3 = octet_sum(p3);

            // ---- redistribute to standard layout: lane j wants m[j&31] ----
            const float m0 = bpermute_f(idxR, p0);
            const float m1 = bpermute_f(idxR, p1);
            const float m2 = bpermute_f(idxR, p2);
            const float m3 = bpermute_f(idxR, p3);
            const float t0 = selA ? m1 : m0;
            const float t1 = selA ? m3 : m2;
            const float m  = selB ? t1 : t0;

            // ---- combine ----
            const float n2 = readlane_f(red, 31);
            const float rn = rsqrtf(n2 + 1e-24f);       // 0*huge = 0 at t=0
            w = fmaf(m, rn, creg[j]);

            // ---- prefetch row t+j+DPRE into this slot ----
            int tn = t + j + DPRE;
            if (tn > L_ - 1) tn = L_ - 1;
            const float* ap = At + (size_t)tn * 1024;
            #pragma unroll
            for (int q = 0; q < 4; ++q) areg[j][q] = *(const float4*)(ap + 256 * q);
            creg[j] = cb[tn * 32];
        }
    }
}

// ---------------------------------------------------------------------------
// Phase B: normalize stored w -> left = h + u; M = left.site; fused bridge.
// ---------------------------------------------------------------------------
__global__ __launch_bounds__(128) void phaseB_kernel(
    const float* __restrict__ site, const float* __restrict__ x,
    const float* __restrict__ wBuf,
    const float* __restrict__ Wb, const float* __restrict__ bb,
    float* __restrict__ y1)
{
    __shared__ float lf[32];
    __shared__ float Ml[128];
    __shared__ float part[4][32];

    const int bt = blockIdx.x;
    const int tid = threadIdx.x;

    if (tid < 64) {
        const float wv = wBuf[(size_t)bt * 64 + tid];
        float red = reduce32_to_lane31(wv * wv);
        const float n2 = readlane_f(red, 31);
        const float rn = rsqrtf(n2 + 1e-24f);
        if (tid < 32)
            lf[tid] = fmaf(wv, rn, x[(size_t)bt * D_ + tid]);  // left = h + u
    }
    __syncthreads();

    const float* sp = site + (size_t)bt * CSC_ + tid;   // tid = p*32+r, l-stride 128
    float acc = 0.f;
    #pragma unroll
    for (int l = 0; l < 32; ++l) acc = fmaf(lf[l], sp[l * 128], acc);
    Ml[tid] = acc;
    __syncthreads();

    const int j = tid & 31, q = tid >> 5;
    float p = 0.f;
    #pragma unroll
    for (int k = 0; k < 32; ++k)
        p = fmaf(Ml[q * 32 + k], Wb[(q * 32 + k) * 32 + j], p);
    part[q][j] = p;
    __syncthreads();

    if (tid < 32)
        y1[bt * 32 + tid] = part[0][tid] + part[1][tid] + part[2][tid]
                          + part[3][tid] + bb[tid];
}

// ---------------------------------------------------------------------------
// Epilogue: y = y1 @ W_out + b_out; LayerNorm; gated residual with x.
// ---------------------------------------------------------------------------
__global__ __launch_bounds__(256) void epilogue_kernel(
    const float* __restrict__ x, const float* __restrict__ y1buf,
    const float* __restrict__ Wout, const float* __restrict__ bout,
    const float* __restrict__ gamma, const float* __restrict__ beta,
    const float* __restrict__ gateZ, float* __restrict__ out)
{
    __shared__ float ys[32];
    __shared__ float red1[4], red2[4];

    const int bt = blockIdx.x;
    const int tid = threadIdx.x;

    if (tid < 32) ys[tid] = y1buf[bt * 32 + tid];
    __syncthreads();

    float yv[2];
    #pragma unroll
    for (int q = 0; q < 2; ++q) {
        const int d = tid + q * 256;
        float acc = bout[d];
        #pragma unroll
        for (int j = 0; j < 32; ++j)
            acc = fmaf(ys[j], Wout[j * D_ + d], acc);
        yv[q] = acc;
    }

    float s1 = yv[0] + yv[1];
    float s2 = yv[0] * yv[0] + yv[1] * yv[1];
    #pragma unroll
    for (int m = 1; m <= 32; m <<= 1) {
        s1 += __shfl_xor(s1, m);
        s2 += __shfl_xor(s2, m);
    }
    const int wid = tid >> 6;
    if ((tid & 63) == 0) { red1[wid] = s1; red2[wid] = s2; }
    __syncthreads();
    const float S1 = red1[0] + red1[1] + red1[2] + red1[3];
    const float S2 = red2[0] + red2[1] + red2[2] + red2[3];
    const float mu  = S1 * (1.f / (float)D_);
    const float var = S2 * (1.f / (float)D_) - mu * mu;
    const float rstd = rsqrtf(var + 1e-6f);

    #pragma unroll
    for (int q = 0; q < 2; ++q) {
        const int d = tid + q * 256;
        const size_t gi = (size_t)bt * D_ + d;
        const float yn = (yv[q] - mu) * rstd * gamma[d] + beta[d];
        const float z = gateZ[gi];
        const float g = 1.f / (1.f + expf(-z));
        const float xv = x[gi];
        out[gi] = g * yn + (1.f - g) * xv;
    }
}

// ---------------------------------------------------------------------------
extern "C" void kernel_launch(void* const* d_in, const int* in_sizes, int n_in,
                              void* d_out, int out_size, void* d_ws, size_t ws_size,
                              hipStream_t stream)
{
    const float* x        = (const float*)d_in[0];
    const float* W_site   = (const float*)d_in[1];
    const float* b_site   = (const float*)d_in[2];
    const float* W_bridge = (const float*)d_in[3];
    const float* b_bridge = (const float*)d_in[4];
    const float* W_out    = (const float*)d_in[5];
    const float* b_out    = (const float*)d_in[6];
    const float* gamma    = (const float*)d_in[7];
    const float* beta     = (const float*)d_in[8];
    const float* W_gate   = (const float*)d_in[9];
    const float* b_gate   = (const float*)d_in[10];
    float* out = (float*)d_out;

    float* ws = (float*)d_ws;
    float* site  = ws;                           // 16,777,216 f (64 MB)
    float* AbarI = site  + (size_t)BT_ * CSC_;   //  4,194,304 f (16 MB)
    float* cBuf  = AbarI + (size_t)BT_ * 1024;   //    131,072 f
    float* wBuf  = cBuf  + (size_t)BT_ * 32;     //    262,144 f
    float* y1    = wBuf  + (size_t)BT_ * 64;     //    131,072 f
    float* gateZ = AbarI;                        // alias: AbarI dead after scan

    // 1. site projection GEMM: site = x @ W_site + b_site   [4096 x 4096]
    gemm_bias_kernel<<<dim3(CSC_ / 64, BT_ / 64), dim3(256), 0, stream>>>(
        x, W_site, b_site, site, BT_, CSC_, D_);

    // 2. prep: interleaved Abar + c = u.Abar  (fully parallel)
    prep_kernel<<<dim3(BT_), dim3(256), 0, stream>>>(site, x, AbarI, cBuf);

    // 3. serial scan (4 waves total) -> w_t
    scan_kernel<<<dim3(B_), dim3(64), 0, stream>>>(AbarI, cBuf, wBuf);

    // 4. phase B: left = w/||w|| + u; M = left.site; fused bridge -> y1
    phaseB_kernel<<<dim3(BT_), dim3(128), 0, stream>>>(
        site, x, wBuf, W_bridge, b_bridge, y1);

    // 5. gate GEMM: gateZ = x @ W_gate + b_gate  (overwrites AbarI region)
    gemm_bias_kernel<<<dim3(D_ / 64, BT_ / 64), dim3(256), 0, stream>>>(
        x, W_gate, b_gate, gateZ, BT_, D_, D_);

    // 6. epilogue: out-proj + LN + gated residual
    epilogue_kernel<<<dim3(BT_), dim3(256), 0, stream>>>(
        x, y1, W_out, b_out, gamma, beta, gateZ, out);
}

// Round 5
// 466.274 us; speedup vs baseline: 1.9298x; 1.2249x over previous
//
#include <hip/hip_runtime.h>
#include <math.h>

// Problem dims (fixed by reference)
#define B_   4
#define L_   1024
#define D_   512
#define CHI_ 32
#define S_   4
#define BT_  (B_ * L_)          // 4096 rows
#define NC_  2560               // fused GEMM width: 1024 AbarI | 1024 G | 512 gate
#define DPRE 8                  // scan prefetch distance (register ring)

// ---------------------------------------------------------------------------
// Cross-lane helpers
// ---------------------------------------------------------------------------
__device__ __forceinline__ float readlane_f(float v, int l) {
    return __int_as_float(__builtin_amdgcn_readlane(__float_as_int(v), l));
}

__device__ __forceinline__ float bpermute_f(int byte_idx, float v) {
    return __int_as_float(__builtin_amdgcn_ds_bpermute(byte_idx, __float_as_int(v)));
}

template <int CTRL>
__device__ __forceinline__ float dpp_add(float x) {
    int y = __builtin_amdgcn_update_dpp(0, __float_as_int(x), CTRL, 0xf, 0xf, true);
    return x + __int_as_float(y);
}

// Sum of lanes 0..31, valid in lane 31 (row_shr moves toward HIGHER lanes).
__device__ __forceinline__ float reduce32_to_lane31(float x) {
    x = dpp_add<0x111>(x);
    x = dpp_add<0x112>(x);
    x = dpp_add<0x114>(x);
    x = dpp_add<0x118>(x);
    x = dpp_add<0x142>(x);  // row_bcast15 -> lane31
    return x;
}

// Octet sum; complete sum lands in the TOP lane of each octet ((lane&7)==7).
__device__ __forceinline__ float octet_sum(float x) {
    x = dpp_add<0x111>(x);
    x = dpp_add<0x112>(x);
    x = dpp_add<0x114>(x);
    return x;
}

// ---------------------------------------------------------------------------
// buildW: fold W_site with (sum_p ·) and with W_bridge; append W_gate.
//   Wcomb[d][f], f in [0,1024):    WA_perm  (scan-interleaved Abar columns)
//   f in [1024,2048):              WW[l*32+j] = sum_pr Ws[d,l*128+pr]*Wb[pr,j]
//   f in [2048,2560):              W_gate[d][f-2048]
// Block 512 == bias block (same folds applied to b_site / b_gate).
// Interleave map: f = 256q+4i+e  ->  l = 4*(i&7)+e,  r = (i>>3)+8q.
// ---------------------------------------------------------------------------
__global__ __launch_bounds__(256) void buildW_kernel(
    const float* __restrict__ Ws, const float* __restrict__ bs,
    const float* __restrict__ Wb, const float* __restrict__ Wg,
    const float* __restrict__ bg, float* __restrict__ Wcomb,
    float* __restrict__ biasC)
{
    const int tid = threadIdx.x;

    if (blockIdx.x == 512) {   // bias block
        for (int f = tid; f < NC_; f += 256) {
            float acc;
            if (f < 1024) {
                const int q = f >> 8, rem = f & 255, i = rem >> 2, e = rem & 3;
                const int l = 4 * (i & 7) + e, r = (i >> 3) + 8 * q;
                const float* p = bs + l * 128 + r;
                acc = p[0] + p[32] + p[64] + p[96];
            } else if (f < 2048) {
                const int g = f - 1024, l = g >> 5, j = g & 31;
                acc = 0.f;
                for (int pr = 0; pr < 128; ++pr)
                    acc = fmaf(bs[l * 128 + pr], Wb[pr * 32 + j], acc);
            } else {
                acc = bg[f - 2048];
            }
            biasC[f] = acc;
        }
        return;
    }

    __shared__ float wsrow[4096];
    __shared__ float wbs[4096];    // Wb[pr][j], pr*32+j

    const int d = blockIdx.x;
    #pragma unroll
    for (int i = 0; i < 16; ++i) {
        wsrow[i * 256 + tid] = Ws[(size_t)d * 4096 + i * 256 + tid];
        wbs[i * 256 + tid]   = Wb[i * 256 + tid];
    }
    __syncthreads();

    float* wrow = Wcomb + (size_t)d * NC_;

    // WA (interleaved): 4 cols/thread
    #pragma unroll
    for (int ii = 0; ii < 4; ++ii) {
        const int f = ii * 256 + tid;
        const int q = f >> 8, rem = f & 255, i = rem >> 2, e = rem & 3;
        const int l = 4 * (i & 7) + e, r = (i >> 3) + 8 * q;
        const float* p = wsrow + l * 128 + r;
        wrow[f] = p[0] + p[32] + p[64] + p[96];
    }
    // WW: 4 cols/thread, 128 FMA each
    #pragma unroll
    for (int ii = 0; ii < 4; ++ii) {
        const int g = ii * 256 + tid;
        const int l = g >> 5, j = g & 31;
        float acc = 0.f;
        #pragma unroll 8
        for (int pr = 0; pr < 128; ++pr)
            acc = fmaf(wsrow[l * 128 + pr], wbs[pr * 32 + j], acc);
        wrow[1024 + g] = acc;
    }
    // gate copy: 2 cols/thread
    #pragma unroll
    for (int ii = 0; ii < 2; ++ii) {
        const int c = ii * 256 + tid;
        wrow[2048 + c] = Wg[(size_t)d * 512 + c];
    }
}

// ---------------------------------------------------------------------------
// Generic fp32 GEMM with bias: C[M,N] = A[M,K] @ B[K,N] + bias[N]
// ---------------------------------------------------------------------------
__global__ __launch_bounds__(256) void gemm_bias_kernel(
    const float* __restrict__ A, const float* __restrict__ Bm,
    const float* __restrict__ bias, float* __restrict__ C,
    int M, int N, int K)
{
    __shared__ float As[32][68];
    __shared__ float Bs[32][64];

    const int tid = threadIdx.x;
    const int tx = tid & 15;
    const int ty = tid >> 4;
    const int m0 = blockIdx.y * 64;
    const int n0 = blockIdx.x * 64;

    float c[4][4] = {};

    for (int k0 = 0; k0 < K; k0 += 32) {
        {
            const int o = tid * 8;
            const int m = o >> 5;
            const int k = o & 31;
            const float* ap = A + (size_t)(m0 + m) * K + k0 + k;
            const float4 a0 = *(const float4*)ap;
            const float4 a1 = *(const float4*)(ap + 4);
            As[k + 0][m] = a0.x; As[k + 1][m] = a0.y;
            As[k + 2][m] = a0.z; As[k + 3][m] = a0.w;
            As[k + 4][m] = a1.x; As[k + 5][m] = a1.y;
            As[k + 6][m] = a1.z; As[k + 7][m] = a1.w;
        }
        {
            const int o = tid * 8;
            const int k = o >> 6;
            const int n = o & 63;
            const float* bp = Bm + (size_t)(k0 + k) * N + n0 + n;
            *(float4*)&Bs[k][n]     = *(const float4*)bp;
            *(float4*)&Bs[k][n + 4] = *(const float4*)(bp + 4);
        }
        __syncthreads();

        #pragma unroll
        for (int kk = 0; kk < 32; ++kk) {
            const float4 av = *(const float4*)&As[kk][ty * 4];
            const float4 bv = *(const float4*)&Bs[kk][tx * 4];
            const float a[4] = {av.x, av.y, av.z, av.w};
            const float b[4] = {bv.x, bv.y, bv.z, bv.w};
            #pragma unroll
            for (int i = 0; i < 4; ++i)
                #pragma unroll
                for (int j = 0; j < 4; ++j)
                    c[i][j] = fmaf(a[i], b[j], c[i][j]);
        }
        __syncthreads();
    }

    const float4 bv = *(const float4*)&bias[n0 + tx * 4];
    #pragma unroll
    for (int i = 0; i < 4; ++i) {
        float4 outv;
        outv.x = c[i][0] + bv.x;
        outv.y = c[i][1] + bv.y;
        outv.z = c[i][2] + bv.z;
        outv.w = c[i][3] + bv.w;
        *(float4*)&C[(size_t)(m0 + ty * 4 + i) * N + n0 + tx * 4] = outv;
    }
}

// ---------------------------------------------------------------------------
// cvec: c[bt][r] = sum_l u[l]*Abar[l][r], u = x[bt,0:32]. AbarI is the
// interleaved block at C[bt*NC_ + 0..1024). Same bpermute/octet machinery as
// the scan, one wave per bt (4 bt per 256-thread block).
// ---------------------------------------------------------------------------
__global__ __launch_bounds__(256) void cvec_kernel(
    const float* __restrict__ Cc, const float* __restrict__ x,
    float* __restrict__ cBuf)
{
    const int tid  = threadIdx.x;
    const int lane = tid & 63;
    const int bt   = blockIdx.x * 4 + (tid >> 6);

    const float* base = Cc + (size_t)bt * NC_ + 4 * lane;
    float4 a0 = *(const float4*)(base + 0);
    float4 a1 = *(const float4*)(base + 256);
    float4 a2 = *(const float4*)(base + 512);
    float4 a3 = *(const float4*)(base + 768);

    const float u = x[(size_t)bt * D_ + (lane & 31)];
    const int idx0 = 16 * (lane & 7);
    const float u0 = bpermute_f(idx0 + 0,  u);
    const float u1 = bpermute_f(idx0 + 4,  u);
    const float u2 = bpermute_f(idx0 + 8,  u);
    const float u3 = bpermute_f(idx0 + 12, u);

    float p0 = fmaf(u3, a0.w, fmaf(u2, a0.z, fmaf(u1, a0.y, u0 * a0.x)));
    float p1 = fmaf(u3, a1.w, fmaf(u2, a1.z, fmaf(u1, a1.y, u0 * a1.x)));
    float p2 = fmaf(u3, a2.w, fmaf(u2, a2.z, fmaf(u1, a2.y, u0 * a2.x)));
    float p3 = fmaf(u3, a3.w, fmaf(u2, a3.z, fmaf(u1, a3.y, u0 * a3.x)));

    p0 = octet_sum(p0); p1 = octet_sum(p1);
    p2 = octet_sum(p2); p3 = octet_sum(p3);

    if ((lane & 7) == 7) {          // top lane of octet k holds m[k+8q]
        const int k = lane >> 3;
        float* cp = cBuf + (size_t)bt * 32 + k;
        cp[0]  = p0;
        cp[8]  = p1;
        cp[16] = p2;
        cp[24] = p3;
    }
}

// ---------------------------------------------------------------------------
// Serial scan, homogeneous form. One wave per batch.
//   w_{t+1} = (w_t . Abar_t) * rsqrt(sum w_t^2) + c_t
// AbarI rows live in C at row stride NC_ (first 1024 columns).
// ---------------------------------------------------------------------------
__global__ __launch_bounds__(64, 1) void scan_kernel(
    const float* __restrict__ Cc, const float* __restrict__ cBuf,
    float* __restrict__ wOut)
{
    const int b   = blockIdx.x;
    const int tid = threadIdx.x;

    const float* At = Cc + (size_t)b * L_ * NC_ + 4 * tid;   // lane base
    const float* cb = cBuf + (size_t)b * L_ * 32 + (tid & 31);
    float*       wo = wOut + (size_t)b * L_ * 64 + tid;

    const int idx0 = 16 * (tid & 7);
    const int idxR = 32 * (tid & 7) + 28;    // octet TOP lane
    const bool selA = (tid >> 3) & 1;
    const bool selB = (tid >> 4) & 1;

    float4 areg[DPRE][4];
    float  creg[DPRE];

    #pragma unroll
    for (int j = 0; j < DPRE; ++j) {
        const float* ap = At + (size_t)j * NC_;
        #pragma unroll
        for (int q = 0; q < 4; ++q) areg[j][q] = *(const float4*)(ap + 256 * q);
        creg[j] = cb[j * 32];
    }

    float w = 0.f;   // w_0 = 0  (h_0 = 0)

    for (int t = 0; t < L_; t += DPRE) {
        #pragma unroll
        for (int j = 0; j < DPRE; ++j) {
            wo[(t + j) * 64] = w;

            float red = reduce32_to_lane31(w * w);

            const float wb0 = bpermute_f(idx0 + 0,  w);
            const float wb1 = bpermute_f(idx0 + 4,  w);
            const float wb2 = bpermute_f(idx0 + 8,  w);
            const float wb3 = bpermute_f(idx0 + 12, w);

            float p0, p1, p2, p3;
            {
                const float4 a0 = areg[j][0], a1 = areg[j][1];
                const float4 a2 = areg[j][2], a3 = areg[j][3];
                p0 = fmaf(wb3, a0.w, fmaf(wb2, a0.z, fmaf(wb1, a0.y, wb0 * a0.x)));
                p1 = fmaf(wb3, a1.w, fmaf(wb2, a1.z, fmaf(wb1, a1.y, wb0 * a1.x)));
                p2 = fmaf(wb3, a2.w, fmaf(wb2, a2.z, fmaf(wb1, a2.y, wb0 * a2.x)));
                p3 = fmaf(wb3, a3.w, fmaf(wb2, a3.z, fmaf(wb1, a3.y, wb0 * a3.x)));
            }

            p0 = octet_sum(p0);
            p1 = octet_sum(p1);
            p2 = octet_sum(p2);
            p3 = octet_sum(p3);

            const float m0 = bpermute_f(idxR, p0);
            const float m1 = bpermute_f(idxR, p1);
            const float m2 = bpermute_f(idxR, p2);
            const float m3 = bpermute_f(idxR, p3);
            const float t0 = selA ? m1 : m0;
            const float t1 = selA ? m3 : m2;
            const float m  = selB ? t1 : t0;

            const float n2 = readlane_f(red, 31);
            const float rn = rsqrtf(n2 + 1e-24f);
            w = fmaf(m, rn, creg[j]);

            int tn = t + j + DPRE;
            if (tn > L_ - 1) tn = L_ - 1;
            const float* ap = At + (size_t)tn * NC_;
            #pragma unroll
            for (int q = 0; q < 4; ++q) areg[j][q] = *(const float4*)(ap + 256 * q);
            creg[j] = cb[tn * 32];
        }
    }
}

// ---------------------------------------------------------------------------
// Phase B: left = w/||w|| + u; y1[j] = sum_l left[l]*G[l*32+j] + bb[j],
// where G is C[bt*NC_ + 1024 ..2048).
// ---------------------------------------------------------------------------
__global__ __launch_bounds__(128) void phaseB_kernel(
    const float* __restrict__ Cc, const float* __restrict__ x,
    const float* __restrict__ wBuf, const float* __restrict__ bb,
    float* __restrict__ y1)
{
    __shared__ float lf[32];
    __shared__ float part[4][32];

    const int bt = blockIdx.x;
    const int tid = threadIdx.x;

    if (tid < 64) {
        const float wv = wBuf[(size_t)bt * 64 + tid];
        float red = reduce32_to_lane31(wv * wv);
        const float n2 = readlane_f(red, 31);
        const float rn = rsqrtf(n2 + 1e-24f);
        if (tid < 32)
            lf[tid] = fmaf(wv, rn, x[(size_t)bt * D_ + tid]);  // left = h + u
    }
    __syncthreads();

    const int j = tid & 31, q = tid >> 5;
    const float* Gp = Cc + (size_t)bt * NC_ + 1024;
    float p = 0.f;
    #pragma unroll
    for (int i = 0; i < 8; ++i)
        p = fmaf(lf[8 * q + i], Gp[(8 * q + i) * 32 + j], p);
    part[q][j] = p;
    __syncthreads();

    if (tid < 32)
        y1[bt * 32 + tid] = part[0][tid] + part[1][tid] + part[2][tid]
                          + part[3][tid] + bb[tid];
}

// ---------------------------------------------------------------------------
// Epilogue: y = y1 @ W_out + b_out; LayerNorm; gated residual with x.
// gate logits live in C[bt*NC_ + 2048 ..2560).
// ---------------------------------------------------------------------------
__global__ __launch_bounds__(256) void epilogue_kernel(
    const float* __restrict__ x, const float* __restrict__ y1buf,
    const float* __restrict__ Wout, const float* __restrict__ bout,
    const float* __restrict__ gamma, const float* __restrict__ beta,
    const float* __restrict__ Cc, float* __restrict__ out)
{
    __shared__ float ys[32];
    __shared__ float red1[4], red2[4];

    const int bt = blockIdx.x;
    const int tid = threadIdx.x;

    if (tid < 32) ys[tid] = y1buf[bt * 32 + tid];
    __syncthreads();

    float yv[2];
    #pragma unroll
    for (int q = 0; q < 2; ++q) {
        const int d = tid + q * 256;
        float acc = bout[d];
        #pragma unroll
        for (int j = 0; j < 32; ++j)
            acc = fmaf(ys[j], Wout[j * D_ + d], acc);
        yv[q] = acc;
    }

    float s1 = yv[0] + yv[1];
    float s2 = yv[0] * yv[0] + yv[1] * yv[1];
    #pragma unroll
    for (int m = 1; m <= 32; m <<= 1) {
        s1 += __shfl_xor(s1, m);
        s2 += __shfl_xor(s2, m);
    }
    const int wid = tid >> 6;
    if ((tid & 63) == 0) { red1[wid] = s1; red2[wid] = s2; }
    __syncthreads();
    const float S1 = red1[0] + red1[1] + red1[2] + red1[3];
    const float S2 = red2[0] + red2[1] + red2[2] + red2[3];
    const float mu  = S1 * (1.f / (float)D_);
    const float var = S2 * (1.f / (float)D_) - mu * mu;
    const float rstd = rsqrtf(var + 1e-6f);

    #pragma unroll
    for (int q = 0; q < 2; ++q) {
        const int d = tid + q * 256;
        const size_t gi = (size_t)bt * D_ + d;
        const float yn = (yv[q] - mu) * rstd * gamma[d] + beta[d];
        const float z = Cc[(size_t)bt * NC_ + 2048 + d];
        const float g = 1.f / (1.f + expf(-z));
        const float xv = x[gi];
        out[gi] = g * yn + (1.f - g) * xv;
    }
}

// ---------------------------------------------------------------------------
extern "C" void kernel_launch(void* const* d_in, const int* in_sizes, int n_in,
                              void* d_out, int out_size, void* d_ws, size_t ws_size,
                              hipStream_t stream)
{
    const float* x        = (const float*)d_in[0];
    const float* W_site   = (const float*)d_in[1];
    const float* b_site   = (const float*)d_in[2];
    const float* W_bridge = (const float*)d_in[3];
    const float* b_bridge = (const float*)d_in[4];
    const float* W_out    = (const float*)d_in[5];
    const float* b_out    = (const float*)d_in[6];
    const float* gamma    = (const float*)d_in[7];
    const float* beta     = (const float*)d_in[8];
    const float* W_gate   = (const float*)d_in[9];
    const float* b_gate   = (const float*)d_in[10];
    float* out = (float*)d_out;

    float* ws = (float*)d_ws;
    float* Wcomb = ws;                            //   512*2560 = 1,310,720 f
    float* biasC = Wcomb + (size_t)512 * NC_;     //        2,560 f
    float* Cc    = biasC + NC_;                   // 4096*2560 = 10,485,760 f (42 MB)
    float* cBuf  = Cc    + (size_t)BT_ * NC_;     //      131,072 f
    float* wBuf  = cBuf  + (size_t)BT_ * 32;      //      262,144 f
    float* y1    = wBuf  + (size_t)BT_ * 64;      //      131,072 f

    // 0. fold weights: [WA_perm | WW | W_gate] + fused bias
    buildW_kernel<<<dim3(513), dim3(256), 0, stream>>>(
        W_site, b_site, W_bridge, W_gate, b_gate, Wcomb, biasC);

    // 1. one fused GEMM: C = x @ Wcomb + biasC   [4096 x 2560, K=512]
    gemm_bias_kernel<<<dim3(NC_ / 64, BT_ / 64), dim3(256), 0, stream>>>(
        x, Wcomb, biasC, Cc, BT_, NC_, D_);

    // 2. c vectors: c = u . Abar  (fully parallel)
    cvec_kernel<<<dim3(BT_ / 4), dim3(256), 0, stream>>>(Cc, x, cBuf);

    // 3. serial scan (4 waves total) -> w_t
    scan_kernel<<<dim3(B_), dim3(64), 0, stream>>>(Cc, cBuf, wBuf);

    // 4. phase B: y1 = left . G + bb
    phaseB_kernel<<<dim3(BT_), dim3(128), 0, stream>>>(
        Cc, x, wBuf, b_bridge, y1);

    // 5. epilogue: out-proj + LN + gated residual (gate from C)
    epilogue_kernel<<<dim3(BT_), dim3(256), 0, stream>>>(
        x, y1, W_out, b_out, gamma, beta, Cc, out);
}